// Round 14
// baseline (363.373 us; speedup 1.0000x reference)
//
#include <hip/hip_runtime.h>
#include <hip/hip_fp16.h>

#define N_NODES 100000
#define N_EDGES 3200000
#define N_GRAPHS 64
#define IN_DIM 128
#define HIDDEN 64
#define LATENT 16

#define NB 1024         // fine buckets (128 nodes each), node>>7
#define BSH 7
#define NB_USED 782     // ceil(100000/128)
#define SC_BLOCKS 256
#define NKEYS 1024      // sub(2) x chunk(8) x owner(8) x row(8)
#define NBLK_AGG 1563   // 64-node aggregate blocks
#define SEG_INTS (1565 * 64)

// ---------------- tiny zero kernel ----------------
__global__ __launch_bounds__(256) void zero_k(int4* __restrict__ p, int n4) {
  int i = blockIdx.x * 256 + threadIdx.x;
  if (i < n4) p[i] = make_int4(0, 0, 0, 0);
}

// ---------------- pass A: 1024-bucket histograms; dump per-block counts ----------------
__global__ __launch_bounds__(256) void hist_c_k(const int4* __restrict__ src4,
                                                const int4* __restrict__ dst4,
                                                int* __restrict__ bc_src,
                                                int* __restrict__ bc_dst,
                                                int* __restrict__ tbl_src,
                                                int* __restrict__ tbl_dst) {
  __shared__ int hs[NB], hd[NB];
  int t = threadIdx.x;
  for (int i = t; i < NB; i += 256) { hs[i] = 0; hd[i] = 0; }
  __syncthreads();
  const int Q = N_EDGES / 4;
  const int QPB = Q / SC_BLOCKS;   // 3125
  int q0 = blockIdx.x * QPB, q1 = q0 + QPB;
  for (int i = q0 + t; i < q1; i += 256) {
    int4 s = src4[i], d = dst4[i];
    atomicAdd(&hs[s.x >> BSH], 1); atomicAdd(&hs[s.y >> BSH], 1);
    atomicAdd(&hs[s.z >> BSH], 1); atomicAdd(&hs[s.w >> BSH], 1);
    atomicAdd(&hd[d.x >> BSH], 1); atomicAdd(&hd[d.y >> BSH], 1);
    atomicAdd(&hd[d.z >> BSH], 1); atomicAdd(&hd[d.w >> BSH], 1);
  }
  __syncthreads();
  for (int i = t; i < NB; i += 256) {
    int a = hs[i], b = hd[i];
    tbl_src[blockIdx.x * NB + i] = a;
    tbl_dst[blockIdx.x * NB + i] = b;
    if (a) atomicAdd(&bc_src[i], a);
    if (b) atomicAdd(&bc_dst[i], b);
  }
}

// ---------------- pass B: exclusive scans over 1024 entries (4/thread) ----------------
__global__ __launch_bounds__(256) void scan_c_k(const int* __restrict__ bc_src,
                                                const int* __restrict__ bc_dst,
                                                int* __restrict__ bbase_src,
                                                int* __restrict__ bbase_dst) {
  __shared__ int ts[256];
  int t = threadIdx.x;
  int b4 = 4 * t;
  // src
  {
    int a0 = bc_src[b4], a1 = bc_src[b4 + 1], a2 = bc_src[b4 + 2], a3 = bc_src[b4 + 3];
    int s = a0 + a1 + a2 + a3;
    ts[t] = s;
    __syncthreads();
    for (int off = 1; off < 256; off <<= 1) {
      int x = 0;
      if (t >= off) x = ts[t - off];
      __syncthreads();
      if (t >= off) ts[t] += x;
      __syncthreads();
    }
    int run = ts[t] - s;
    bbase_src[b4] = run;
    bbase_src[b4 + 1] = run + a0;
    bbase_src[b4 + 2] = run + a0 + a1;
    bbase_src[b4 + 3] = run + a0 + a1 + a2;
    if (t == 255) bbase_src[NB] = ts[255];
    __syncthreads();
  }
  // dst
  {
    int a0 = bc_dst[b4], a1 = bc_dst[b4 + 1], a2 = bc_dst[b4 + 2], a3 = bc_dst[b4 + 3];
    int s = a0 + a1 + a2 + a3;
    ts[t] = s;
    __syncthreads();
    for (int off = 1; off < 256; off <<= 1) {
      int x = 0;
      if (t >= off) x = ts[t - off];
      __syncthreads();
      if (t >= off) ts[t] += x;
      __syncthreads();
    }
    int run = ts[t] - s;
    bbase_dst[b4] = run;
    bbase_dst[b4 + 1] = run + a0;
    bbase_dst[b4 + 2] = run + a0 + a1;
    bbase_dst[b4 + 3] = run + a0 + a1 + a2;
    if (t == 255) bbase_dst[NB] = ts[255];
  }
}

// ---------------- pass C: scatter into 1024 buckets; sortedE packs (d7<<17)|src ----
__global__ __launch_bounds__(256) void scatter_c_k(const int4* __restrict__ src4,
                                                   const int4* __restrict__ dst4,
                                                   const int* __restrict__ bbase_src,
                                                   const int* __restrict__ bbase_dst,
                                                   const int* __restrict__ tbl_src,
                                                   const int* __restrict__ tbl_dst,
                                                   int* __restrict__ cur_src,
                                                   int* __restrict__ cur_dst,
                                                   int* __restrict__ sortedS,
                                                   int* __restrict__ sortedE) {
  __shared__ int rs[NB], rd[NB];
  int t = threadIdx.x;
  for (int i = t; i < NB; i += 256) {
    int a = tbl_src[blockIdx.x * NB + i];
    int b = tbl_dst[blockIdx.x * NB + i];
    rs[i] = a ? (atomicAdd(&cur_src[i], a) + bbase_src[i]) : 0;
    rd[i] = b ? (atomicAdd(&cur_dst[i], b) + bbase_dst[i]) : 0;
  }
  __syncthreads();
  const int Q = N_EDGES / 4;
  const int QPB = Q / SC_BLOCKS;
  int q0 = blockIdx.x * QPB, q1 = q0 + QPB;
  for (int i = q0 + t; i < q1; i += 256) {
    int4 s = src4[i], d = dst4[i];
    int sv[4] = {s.x, s.y, s.z, s.w};
    int dv[4] = {d.x, d.y, d.z, d.w};
#pragma unroll
    for (int k = 0; k < 4; k++) {
      int ps = atomicAdd(&rs[sv[k] >> BSH], 1);
      sortedS[ps] = sv[k];
      int pd = atomicAdd(&rd[dv[k] >> BSH], 1);
      sortedE[pd] = ((dv[k] & 127) << 17) | sv[k];
    }
  }
}

// ---------------- pass D: per-fine-bucket sort by (sub64, chunk, owner, dstrow) ----
// 782 blocks (128 nodes each), 1024 keys, ~9KB LDS -> high occupancy (R13 fine_sort
// ran 196 blocks = 10% occupancy).
__global__ __launch_bounds__(256) void fine_sort_k(const int* __restrict__ sortedE,
                                                   const int* __restrict__ bbase_dst,
                                                   int* __restrict__ deg_in,
                                                   int* __restrict__ seg,
                                                   int* __restrict__ eblk) {
  __shared__ int hist[NKEYS];
  __shared__ int cur[NKEYS];
  __shared__ int ts[256];
  int bk = blockIdx.x, t = threadIdx.x;
  int node0 = bk << BSH;
  int e0 = bbase_dst[bk], e1 = bbase_dst[bk + 1];
  for (int i = t; i < NKEYS; i += 256) hist[i] = 0;
  __syncthreads();
  // key = sub(1b)<<9 | chunk<<6 | owner<<3 | row
  for (int j = e0 + t; j < e1; j += 256) {
    int v = sortedE[j];
    int d7 = v >> 17, sr = v & 0x1FFFF;
    int key = ((d7 >> 6) << 9) | ((sr >> 14) << 6) | ((d7 & 7) << 3) | ((d7 >> 3) & 7);
    atomicAdd(&hist[key], 1);
  }
  __syncthreads();
  // exclusive scan over 1024 keys (4/thread)
  int b4 = 4 * t;
  int a0 = hist[b4], a1 = hist[b4 + 1], a2 = hist[b4 + 2], a3 = hist[b4 + 3];
  int s = a0 + a1 + a2 + a3;
  ts[t] = s;
  __syncthreads();
  for (int off = 1; off < 256; off <<= 1) {
    int x = 0;
    if (t >= off) x = ts[t - off];
    __syncthreads();
    if (t >= off) ts[t] += x;
    __syncthreads();
  }
  int run = ts[t] - s;
  cur[b4] = run;
  cur[b4 + 1] = run + a0;
  cur[b4 + 2] = run + a0 + a1;
  cur[b4 + 3] = run + a0 + a1 + a2;
  __syncthreads();
  // deg_in for 128 nodes
  if (t < 128) {
    int n = node0 + t;
    if (n < N_NODES) {
      int sub = t >> 6, o = t & 7, row = (t >> 3) & 7;
      int base = (sub << 9) | (o << 3) | row;
      int dg = 0;
#pragma unroll
      for (int c = 0; c < 8; c++) dg += hist[base + (c << 6)];
      deg_in[n] = dg;
    }
  }
  // seg offsets: 2 agg blocks x 8 chunks x 8 owners = 128 entries
  if (t < 128) {
    int sub = t >> 6, c = (t >> 3) & 7, o = t & 7;
    seg[(bk * 2 + sub) * 64 + c * 8 + o] = e0 + cur[(sub << 9) | (c << 6) | (o << 3)];
  }
  __syncthreads();
  // scatter into eblk, repacked as (d6<<17)|src
  for (int j = e0 + t; j < e1; j += 256) {
    int v = sortedE[j];
    int d7 = v >> 17, sr = v & 0x1FFFF;
    int key = ((d7 >> 6) << 9) | ((sr >> 14) << 6) | ((d7 & 7) << 3) | ((d7 >> 3) & 7);
    int pos = e0 + atomicAdd(&cur[key], 1);
    eblk[pos] = ((d7 & 63) << 17) | sr;
  }
}

// ---------------- deg_out: per fine src-bucket LDS hist over sortedS ----------------
__global__ __launch_bounds__(256) void degout_c_k(const int* __restrict__ sortedS,
                                                  const int* __restrict__ bbase_src,
                                                  int* __restrict__ deg_out) {
  __shared__ int h[128];
  int bk = blockIdx.x, t = threadIdx.x;
  if (t < 128) h[t] = 0;
  __syncthreads();
  int s0 = bbase_src[bk], s1 = bbase_src[bk + 1];
  for (int j = s0 + t; j < s1; j += 256) atomicAdd(&h[sortedS[j] & 127], 1);
  __syncthreads();
  if (t < 128) {
    int n = (bk << BSH) | t;
    if (n < N_NODES) deg_out[n] = h[t];
  }
}

// ---------------- per-graph node counts ----------------
__global__ __launch_bounds__(256) void counts_k(const int* __restrict__ node_graph,
                                                float* __restrict__ counts) {
  __shared__ int h[N_GRAPHS];
  int t = threadIdx.x;
  if (t < N_GRAPHS) h[t] = 0;
  __syncthreads();
  int base = blockIdx.x * 1024;
  int end = base + 1024; if (end > N_NODES) end = N_NODES;
  for (int i = base + t; i < end; i += 256) atomicAdd(&h[node_graph[i]], 1);
  __syncthreads();
  if (t < N_GRAPHS && h[t]) atomicAdd(&counts[t], (float)h[t]);
}

// ---------------- register-tiled GEMM: out[n][c] = (X@W)[n][c] * rsqrt(max(deg,1)) ----
template <int IN, typename IT, typename OT>
__global__ __launch_bounds__(256) void gemm_tile_k(const IT* __restrict__ X,
                                                   const float* __restrict__ W,
                                                   const int* __restrict__ deg,
                                                   OT* __restrict__ out) {
  __shared__ float xs[64][IN + 4];
  __shared__ float ws[IN][HIDDEN];
  int t = threadIdx.x;
  int row0_blk = blockIdx.x * 64;

  for (int i = t; i < IN * HIDDEN / 4; i += 256)
    ((float4*)ws)[i] = ((const float4*)W)[i];
  for (int i = t; i < 64 * (IN / 4); i += 256) {
    int r = i / (IN / 4), c4 = i % (IN / 4);
    int row = row0_blk + r;
    float4 v = make_float4(0.f, 0.f, 0.f, 0.f);
    if (row < N_NODES) {
      if constexpr (sizeof(IT) == 4) {
        v = *(const float4*)&X[(size_t)row * IN + c4 * 4];
      } else {
        union { short4 s; __half2 h2[2]; } u;
        u.s = *(const short4*)&X[(size_t)row * IN + c4 * 4];
        float2 f0 = __half22float2(u.h2[0]);
        float2 f1 = __half22float2(u.h2[1]);
        v = make_float4(f0.x, f0.y, f1.x, f1.y);
      }
    }
    *(float4*)&xs[r][c4 * 4] = v;
  }
  __syncthreads();

  int w = t >> 6, lane = t & 63;
  int rg = lane >> 4, cg = lane & 15;
  int r0 = w * 16 + rg * 4;
  int c0 = cg * 4;

  float acc[4][4];
#pragma unroll
  for (int i = 0; i < 4; i++)
#pragma unroll
    for (int j = 0; j < 4; j++) acc[i][j] = 0.f;

#pragma unroll 4
  for (int d4 = 0; d4 < IN / 4; d4++) {
    float4 a0 = *(const float4*)&xs[r0 + 0][d4 * 4];
    float4 a1 = *(const float4*)&xs[r0 + 1][d4 * 4];
    float4 a2 = *(const float4*)&xs[r0 + 2][d4 * 4];
    float4 a3 = *(const float4*)&xs[r0 + 3][d4 * 4];
#pragma unroll
    for (int dd = 0; dd < 4; dd++) {
      float4 b = *(const float4*)&ws[d4 * 4 + dd][c0];
      float av0 = (&a0.x)[dd], av1 = (&a1.x)[dd], av2 = (&a2.x)[dd], av3 = (&a3.x)[dd];
      acc[0][0] += av0 * b.x; acc[0][1] += av0 * b.y; acc[0][2] += av0 * b.z; acc[0][3] += av0 * b.w;
      acc[1][0] += av1 * b.x; acc[1][1] += av1 * b.y; acc[1][2] += av1 * b.z; acc[1][3] += av1 * b.w;
      acc[2][0] += av2 * b.x; acc[2][1] += av2 * b.y; acc[2][2] += av2 * b.z; acc[2][3] += av2 * b.w;
      acc[3][0] += av3 * b.x; acc[3][1] += av3 * b.y; acc[3][2] += av3 * b.z; acc[3][3] += av3 * b.w;
    }
  }

#pragma unroll
  for (int i = 0; i < 4; i++) {
    int row = row0_blk + r0 + i;
    if (row >= N_NODES) continue;
    float dg = (float)deg[row];
    if (dg < 1.f) dg = 1.f;
    float sc = rsqrtf(dg);
    if constexpr (sizeof(OT) == 2) {
      __half2 p0 = __floats2half2_rn(acc[i][0] * sc, acc[i][1] * sc);
      __half2 p1 = __floats2half2_rn(acc[i][2] * sc, acc[i][3] * sc);
      union { __half2 h2[2]; float2 f2; } u;
      u.h2[0] = p0; u.h2[1] = p1;
      *(float2*)&out[(size_t)row * HIDDEN + c0] = u.f2;
    } else {
      float4 o = make_float4(acc[i][0] * sc, acc[i][1] * sc, acc[i][2] * sc, acc[i][3] * sc);
      *(float4*)&out[(size_t)row * HIDDEN + c0] = o;
    }
  }
}

// ---------------- aggregate: block=64 dst nodes, chunk-swept, owner-exclusive LDS ----
// MODE 1: fuse gemm2 (W2 from global, L1-hot). MODE 2: fuse mean-pool partials.
// LDS ~17.7KB -> 8 blocks/CU -> all 1563 blocks co-resident (required for the
// lockstep chunk sweep; see R11 post-mortem).
template <int MODE>
__global__ __launch_bounds__(256) void agg_seg_k(const __half* __restrict__ A,
                                                 const int* __restrict__ eblk,
                                                 const int* __restrict__ seg,
                                                 const int* __restrict__ deg_in,
                                                 const float* __restrict__ bias,
                                                 const float* __restrict__ W2,
                                                 const int* __restrict__ deg_out,
                                                 const int* __restrict__ node_graph,
                                                 float* __restrict__ sums,
                                                 __half* __restrict__ out) {
  __shared__ float acc[64][68];   // 17408 B
  __shared__ int ngs[64];
  __shared__ float psum[4][64];
  int bk = blockIdx.x, t = threadIdx.x;
  int o = t >> 5, l = t & 31;
  for (int i = t; i < 64 * 68; i += 256) ((float*)acc)[i] = 0.f;
  __syncthreads();
  int segbase = bk * 64;
  float rx = 0.f, ry = 0.f;
  int cur_d = -1;
#pragma unroll
  for (int c = 0; c < 8; c++) {
    int j0 = seg[segbase + c * 8 + o];
    int j1 = seg[segbase + c * 8 + o + 1];
    int j = j0;
    for (; j + 16 <= j1; j += 16) {
      int ev = eblk[j + (l & 15)];
      int vv[16];
#pragma unroll
      for (int k = 0; k < 16; k++) vv[k] = __shfl(ev, k, 32);
      float2 ff[16];
#pragma unroll
      for (int k = 0; k < 16; k++)
        ff[k] = __half22float2(*(const __half2*)&A[(size_t)(vv[k] & 0x1FFFF) * HIDDEN + 2 * l]);
#pragma unroll
      for (int k = 0; k < 16; k++) {
        int d = vv[k] >> 17;
        if (d != cur_d) {
          if (cur_d >= 0) {
            float2* ap = (float2*)&acc[cur_d][2 * l];
            float2 a0 = *ap; a0.x += rx; a0.y += ry; *ap = a0;
          }
          cur_d = d; rx = 0.f; ry = 0.f;
        }
        rx += ff[k].x; ry += ff[k].y;
      }
    }
    for (; j + 4 <= j1; j += 4) {
      int vv[4];
#pragma unroll
      for (int k = 0; k < 4; k++) vv[k] = eblk[j + k];
      float2 ff[4];
#pragma unroll
      for (int k = 0; k < 4; k++)
        ff[k] = __half22float2(*(const __half2*)&A[(size_t)(vv[k] & 0x1FFFF) * HIDDEN + 2 * l]);
#pragma unroll
      for (int k = 0; k < 4; k++) {
        int d = vv[k] >> 17;
        if (d != cur_d) {
          if (cur_d >= 0) {
            float2* ap = (float2*)&acc[cur_d][2 * l];
            float2 a0 = *ap; a0.x += rx; a0.y += ry; *ap = a0;
          }
          cur_d = d; rx = 0.f; ry = 0.f;
        }
        rx += ff[k].x; ry += ff[k].y;
      }
    }
    for (; j < j1; j++) {
      int v = eblk[j];
      int d = v >> 17;
      if (d != cur_d) {
        if (cur_d >= 0) {
          float2* ap = (float2*)&acc[cur_d][2 * l];
          float2 a0 = *ap; a0.x += rx; a0.y += ry; *ap = a0;
        }
        cur_d = d; rx = 0.f; ry = 0.f;
      }
      float2 f = __half22float2(*(const __half2*)&A[(size_t)(v & 0x1FFFF) * HIDDEN + 2 * l]);
      rx += f.x; ry += f.y;
    }
  }
  if (cur_d >= 0) {
    float2* ap = (float2*)&acc[cur_d][2 * l];
    float2 a0 = *ap; a0.x += rx; a0.y += ry; *ap = a0;
  }
  __syncthreads();

  int node0 = bk << 6;
  if constexpr (MODE == 1) {
    for (int i = t; i < 64 * 64; i += 256) {
      int r = i >> 6, ch = i & 63;
      float dg = (float)deg_in[node0 + r];
      if (dg < 1.f) dg = 1.f;
      float v = acc[r][ch] * rsqrtf(dg) + bias[ch];
      acc[r][ch] = v > 0.f ? v : 0.f;
    }
    __syncthreads();
    int w = t >> 6, lane = t & 63;
    int rg = lane >> 4, cg = lane & 15;
    int r0 = w * 16 + rg * 4;
    int c0 = cg * 4;
    float oacc[4][4];
#pragma unroll
    for (int i = 0; i < 4; i++)
#pragma unroll
      for (int j = 0; j < 4; j++) oacc[i][j] = 0.f;
#pragma unroll 4
    for (int d = 0; d < 64; d++) {
      float4 b = *(const float4*)&W2[d * HIDDEN + c0];
      float a0 = acc[r0 + 0][d], a1 = acc[r0 + 1][d];
      float a2 = acc[r0 + 2][d], a3 = acc[r0 + 3][d];
      oacc[0][0] += a0 * b.x; oacc[0][1] += a0 * b.y; oacc[0][2] += a0 * b.z; oacc[0][3] += a0 * b.w;
      oacc[1][0] += a1 * b.x; oacc[1][1] += a1 * b.y; oacc[1][2] += a1 * b.z; oacc[1][3] += a1 * b.w;
      oacc[2][0] += a2 * b.x; oacc[2][1] += a2 * b.y; oacc[2][2] += a2 * b.z; oacc[2][3] += a2 * b.w;
      oacc[3][0] += a3 * b.x; oacc[3][1] += a3 * b.y; oacc[3][2] += a3 * b.z; oacc[3][3] += a3 * b.w;
    }
#pragma unroll
    for (int i = 0; i < 4; i++) {
      int node = node0 + r0 + i;
      if (node >= N_NODES) continue;
      float dg = (float)deg_out[node];
      if (dg < 1.f) dg = 1.f;
      float sc = rsqrtf(dg);
      __half2 p0 = __floats2half2_rn(oacc[i][0] * sc, oacc[i][1] * sc);
      __half2 p1 = __floats2half2_rn(oacc[i][2] * sc, oacc[i][3] * sc);
      union { __half2 h2[2]; float2 f2; } u;
      u.h2[0] = p0; u.h2[1] = p1;
      *(float2*)&out[(size_t)node * HIDDEN + c0] = u.f2;
    }
  } else {
    if (t < 64) {
      int node = node0 + t;
      ngs[t] = (node < N_NODES) ? node_graph[node] : -1;
    }
    __syncthreads();
    int ch = t & 63, q = t >> 6;
    bool uniform = (ngs[0] >= 0) && (ngs[0] == ngs[63]);
    if (uniform) {
      float a = 0.f;
      for (int r = q * 16; r < q * 16 + 16; r++) {
        float dg = (float)deg_in[node0 + r];
        if (dg < 1.f) dg = 1.f;
        float v = acc[r][ch] * rsqrtf(dg) + bias[ch];
        a += (v > 0.f ? v : 0.f);
      }
      psum[q][ch] = a;
      __syncthreads();
      if (t < 64) {
        float s4 = psum[0][t] + psum[1][t] + psum[2][t] + psum[3][t];
        atomicAdd(&sums[ngs[0] * HIDDEN + t], s4);
      }
    } else {
      int curg = -1; float a = 0.f;
      for (int r = q * 16; r < q * 16 + 16; r++) {
        int g = ngs[r];
        if (g != curg) {
          if (curg >= 0) atomicAdd(&sums[curg * HIDDEN + ch], a);
          curg = g; a = 0.f;
        }
        if (g >= 0) {
          float dg = (float)deg_in[node0 + r];
          if (dg < 1.f) dg = 1.f;
          float v = acc[r][ch] * rsqrtf(dg) + bias[ch];
          a += (v > 0.f ? v : 0.f);
        }
      }
      if (curg >= 0) atomicAdd(&sums[curg * HIDDEN + ch], a);
    }
  }
}

// ---------------- final: h_graph = sums/counts; mu/logvar = h_graph @ Wmu/Wlv + b ----------------
__global__ __launch_bounds__(256) void final_k(const float* __restrict__ sums,
                                               const float* __restrict__ counts,
                                               const float* __restrict__ Wmu,
                                               const float* __restrict__ bmu,
                                               const float* __restrict__ Wlv,
                                               const float* __restrict__ blv,
                                               float* __restrict__ out) {
  __shared__ float hg[N_GRAPHS][HIDDEN];
  __shared__ float wmu[HIDDEN][LATENT];
  __shared__ float wlv[HIDDEN][LATENT];
  int t = threadIdx.x;
  for (int i = t; i < N_GRAPHS * HIDDEN; i += 256) {
    int g = i / HIDDEN;
    float c = counts[g];
    if (c < 1.f) c = 1.f;
    hg[g][i % HIDDEN] = sums[i] / c;
  }
  for (int i = t; i < HIDDEN * LATENT; i += 256) {
    wmu[i / LATENT][i % LATENT] = Wmu[i];
    wlv[i / LATENT][i % LATENT] = Wlv[i];
  }
  __syncthreads();
  for (int i = t; i < N_GRAPHS * LATENT; i += 256) {
    int g = i / LATENT, j = i % LATENT;
    float mu = bmu[j], lv = blv[j];
#pragma unroll
    for (int k = 0; k < HIDDEN; k++) {
      float v = hg[g][k];
      mu += v * wmu[k][j];
      lv += v * wlv[k][j];
    }
    out[i] = mu;
    out[N_GRAPHS * LATENT + i] = lv;
  }
}

extern "C" void kernel_launch(void* const* d_in, const int* in_sizes, int n_in,
                              void* d_out, int out_size, void* d_ws, size_t ws_size,
                              hipStream_t stream) {
  const float* x = (const float*)d_in[0];
  // d_in[1] = edge_feat: provably unused for (mu, logvar)
  const int* src = (const int*)d_in[2];
  const int* dst = (const int*)d_in[3];
  const int* node_graph = (const int*)d_in[4];
  const float* W1 = (const float*)d_in[5];
  const float* b1 = (const float*)d_in[6];
  const float* W2 = (const float*)d_in[7];
  const float* b2 = (const float*)d_in[8];
  // d_in[9] = We, d_in[10] = be: unused
  const float* Wmu = (const float*)d_in[11];
  const float* bmu = (const float*)d_in[12];
  const float* Wlv = (const float*)d_in[13];
  const float* blv = (const float*)d_in[14];
  float* out = (float*)d_out;

  char* ws = (char*)d_ws;
  // zeroed control block [0, 33280)
  int* bc_src   = (int*)(ws + 0);        // 4096
  int* bc_dst   = (int*)(ws + 4096);     // 4096
  int* cur_src  = (int*)(ws + 8192);     // 4096
  int* cur_dst  = (int*)(ws + 12288);    // 4096
  float* cnts   = (float*)(ws + 16384);  // 512
  float* sums   = (float*)(ws + 16896);  // 16384 -> 33280
  // non-zeroed control
  int* bbase_src = (int*)(ws + 33280);   // 4100 (pad 4352)
  int* bbase_dst = (int*)(ws + 37632);   // 4100 (pad)
  int* tbl_src   = (int*)(ws + 41984);   // 1048576
  int* tbl_dst   = (int*)(ws + 1090560); // 1048576 -> 2139136
  // big arrays
  int* deg_out = (int*)(ws + 2139136);   // 400128 -> 2539264
  int* deg_in  = (int*)(ws + 2539264);   // 400128 -> 2939392
  int* seg     = (int*)(ws + 2939392);   // SEG_INTS*4 = 400640 pad -> 3340800
  int* eblk    = (int*)(ws + 3340800);   // 12800000 -> 16140800
  int* sortedS = (int*)(ws + 16140800);  // 12800000 -> 28940800 (dead after degout)
  int* sortedE = (int*)(ws + 28940800);  // 12800000 -> 41740800 (dead after fine_sort)
  __half* A1   = (__half*)(ws + 16140800); // alias of sortedS (layer1 gemm out)
  __half* A2   = (__half*)(ws + 28940800); // alias of sortedE (fused agg1+gemm2 out)

  zero_k<<<(33280 / 16 + 255) / 256, 256, 0, stream>>>((int4*)ws, 33280 / 16);

  hist_c_k<<<SC_BLOCKS, 256, 0, stream>>>((const int4*)src, (const int4*)dst,
                                          bc_src, bc_dst, tbl_src, tbl_dst);
  scan_c_k<<<1, 256, 0, stream>>>(bc_src, bc_dst, bbase_src, bbase_dst);
  scatter_c_k<<<SC_BLOCKS, 256, 0, stream>>>((const int4*)src, (const int4*)dst,
                                             bbase_src, bbase_dst, tbl_src, tbl_dst,
                                             cur_src, cur_dst, sortedS, sortedE);
  fine_sort_k<<<NB_USED, 256, 0, stream>>>(sortedE, bbase_dst, deg_in, seg, eblk);
  degout_c_k<<<NB_USED, 256, 0, stream>>>(sortedS, bbase_src, deg_out);
  counts_k<<<(N_NODES + 1023) / 1024, 256, 0, stream>>>(node_graph, cnts);

  const int GEMM_BLKS = (N_NODES + 63) / 64;  // 1563

  // layer 1 GEMM: A1 = fp16((x @ W1) * deg_out^-1/2)
  gemm_tile_k<IN_DIM, float, __half><<<GEMM_BLKS, 256, 0, stream>>>(x, W1, deg_out, A1);
  // fused agg1 + gemm2: A2 = fp16( (relu(agg(A1)*deg_in^-1/2 + b1) @ W2) * deg_out^-1/2 )
  agg_seg_k<1><<<NBLK_AGG, 256, 0, stream>>>(A1, eblk, seg, deg_in, b1, W2, deg_out,
                                             nullptr, nullptr, A2);
  // fused agg2 + mean-pool: sums += per-graph sums of relu(agg(A2)*deg_in^-1/2 + b2)
  agg_seg_k<2><<<NBLK_AGG, 256, 0, stream>>>(A2, eblk, seg, deg_in, b2, nullptr, nullptr,
                                             node_graph, sums, nullptr);

  final_k<<<1, 256, 0, stream>>>(sums, cnts, Wmu, bmu, Wlv, blv, out);
}

// Round 15
// 312.494 us; speedup vs baseline: 1.1628x; 1.1628x over previous
//
#include <hip/hip_runtime.h>
#include <hip/hip_fp16.h>

#define N_NODES 100000
#define N_EDGES 3200000
#define N_GRAPHS 64
#define IN_DIM 128
#define HIDDEN 64
#define LATENT 16

#define NB 1024         // fine buckets (128 nodes each), node>>7
#define BSH 7
#define NB_USED 782     // ceil(100000/128)
#define SC_BLOCKS 256
#define NKEYS 1024      // sub(2) x chunk(8) x owner(8) x row(8)
#define NBLK_AGG 1563   // 64-node aggregate blocks
#define SEG_INTS (1565 * 64)

// ---------------- tiny zero kernel ----------------
__global__ __launch_bounds__(256) void zero_k(int4* __restrict__ p, int n4) {
  int i = blockIdx.x * 256 + threadIdx.x;
  if (i < n4) p[i] = make_int4(0, 0, 0, 0);
}

// ---------------- pass A: 1024-bucket histograms; dump per-block counts ----------------
__global__ __launch_bounds__(256) void hist_c_k(const int4* __restrict__ src4,
                                                const int4* __restrict__ dst4,
                                                int* __restrict__ bc_src,
                                                int* __restrict__ bc_dst,
                                                int* __restrict__ tbl_src,
                                                int* __restrict__ tbl_dst) {
  __shared__ int hs[NB], hd[NB];
  int t = threadIdx.x;
  for (int i = t; i < NB; i += 256) { hs[i] = 0; hd[i] = 0; }
  __syncthreads();
  const int Q = N_EDGES / 4;
  const int QPB = Q / SC_BLOCKS;   // 3125
  int q0 = blockIdx.x * QPB, q1 = q0 + QPB;
  for (int i = q0 + t; i < q1; i += 256) {
    int4 s = src4[i], d = dst4[i];
    atomicAdd(&hs[s.x >> BSH], 1); atomicAdd(&hs[s.y >> BSH], 1);
    atomicAdd(&hs[s.z >> BSH], 1); atomicAdd(&hs[s.w >> BSH], 1);
    atomicAdd(&hd[d.x >> BSH], 1); atomicAdd(&hd[d.y >> BSH], 1);
    atomicAdd(&hd[d.z >> BSH], 1); atomicAdd(&hd[d.w >> BSH], 1);
  }
  __syncthreads();
  for (int i = t; i < NB; i += 256) {
    int a = hs[i], b = hd[i];
    tbl_src[blockIdx.x * NB + i] = a;
    tbl_dst[blockIdx.x * NB + i] = b;
    if (a) atomicAdd(&bc_src[i], a);
    if (b) atomicAdd(&bc_dst[i], b);
  }
}

// ---------------- pass B: exclusive scans over 1024 entries (4/thread) ----------------
__global__ __launch_bounds__(256) void scan_c_k(const int* __restrict__ bc_src,
                                                const int* __restrict__ bc_dst,
                                                int* __restrict__ bbase_src,
                                                int* __restrict__ bbase_dst) {
  __shared__ int ts[256];
  int t = threadIdx.x;
  int b4 = 4 * t;
  // src
  {
    int a0 = bc_src[b4], a1 = bc_src[b4 + 1], a2 = bc_src[b4 + 2], a3 = bc_src[b4 + 3];
    int s = a0 + a1 + a2 + a3;
    ts[t] = s;
    __syncthreads();
    for (int off = 1; off < 256; off <<= 1) {
      int x = 0;
      if (t >= off) x = ts[t - off];
      __syncthreads();
      if (t >= off) ts[t] += x;
      __syncthreads();
    }
    int run = ts[t] - s;
    bbase_src[b4] = run;
    bbase_src[b4 + 1] = run + a0;
    bbase_src[b4 + 2] = run + a0 + a1;
    bbase_src[b4 + 3] = run + a0 + a1 + a2;
    if (t == 255) bbase_src[NB] = ts[255];
    __syncthreads();
  }
  // dst
  {
    int a0 = bc_dst[b4], a1 = bc_dst[b4 + 1], a2 = bc_dst[b4 + 2], a3 = bc_dst[b4 + 3];
    int s = a0 + a1 + a2 + a3;
    ts[t] = s;
    __syncthreads();
    for (int off = 1; off < 256; off <<= 1) {
      int x = 0;
      if (t >= off) x = ts[t - off];
      __syncthreads();
      if (t >= off) ts[t] += x;
      __syncthreads();
    }
    int run = ts[t] - s;
    bbase_dst[b4] = run;
    bbase_dst[b4 + 1] = run + a0;
    bbase_dst[b4 + 2] = run + a0 + a1;
    bbase_dst[b4 + 3] = run + a0 + a1 + a2;
    if (t == 255) bbase_dst[NB] = ts[255];
  }
}

// ---------------- pass C: scatter into 1024 buckets; sortedE packs (d7<<17)|src ----
__global__ __launch_bounds__(256) void scatter_c_k(const int4* __restrict__ src4,
                                                   const int4* __restrict__ dst4,
                                                   const int* __restrict__ bbase_src,
                                                   const int* __restrict__ bbase_dst,
                                                   const int* __restrict__ tbl_src,
                                                   const int* __restrict__ tbl_dst,
                                                   int* __restrict__ cur_src,
                                                   int* __restrict__ cur_dst,
                                                   int* __restrict__ sortedS,
                                                   int* __restrict__ sortedE) {
  __shared__ int rs[NB], rd[NB];
  int t = threadIdx.x;
  for (int i = t; i < NB; i += 256) {
    int a = tbl_src[blockIdx.x * NB + i];
    int b = tbl_dst[blockIdx.x * NB + i];
    rs[i] = a ? (atomicAdd(&cur_src[i], a) + bbase_src[i]) : 0;
    rd[i] = b ? (atomicAdd(&cur_dst[i], b) + bbase_dst[i]) : 0;
  }
  __syncthreads();
  const int Q = N_EDGES / 4;
  const int QPB = Q / SC_BLOCKS;
  int q0 = blockIdx.x * QPB, q1 = q0 + QPB;
  for (int i = q0 + t; i < q1; i += 256) {
    int4 s = src4[i], d = dst4[i];
    int sv[4] = {s.x, s.y, s.z, s.w};
    int dv[4] = {d.x, d.y, d.z, d.w};
#pragma unroll
    for (int k = 0; k < 4; k++) {
      int ps = atomicAdd(&rs[sv[k] >> BSH], 1);
      sortedS[ps] = sv[k];
      int pd = atomicAdd(&rd[dv[k] >> BSH], 1);
      sortedE[pd] = ((dv[k] & 127) << 17) | sv[k];
    }
  }
}

// ---------------- pass D: per-fine-bucket sort by (sub64, chunk, owner, dstrow) ----
__global__ __launch_bounds__(256) void fine_sort_k(const int* __restrict__ sortedE,
                                                   const int* __restrict__ bbase_dst,
                                                   int* __restrict__ deg_in,
                                                   int* __restrict__ seg,
                                                   int* __restrict__ eblk) {
  __shared__ int hist[NKEYS];
  __shared__ int cur[NKEYS];
  __shared__ int ts[256];
  int bk = blockIdx.x, t = threadIdx.x;
  int node0 = bk << BSH;
  int e0 = bbase_dst[bk], e1 = bbase_dst[bk + 1];
  for (int i = t; i < NKEYS; i += 256) hist[i] = 0;
  __syncthreads();
  // key = sub(1b)<<9 | chunk<<6 | owner<<3 | row
  for (int j = e0 + t; j < e1; j += 256) {
    int v = sortedE[j];
    int d7 = v >> 17, sr = v & 0x1FFFF;
    int key = ((d7 >> 6) << 9) | ((sr >> 14) << 6) | ((d7 & 7) << 3) | ((d7 >> 3) & 7);
    atomicAdd(&hist[key], 1);
  }
  __syncthreads();
  // exclusive scan over 1024 keys (4/thread)
  int b4 = 4 * t;
  int a0 = hist[b4], a1 = hist[b4 + 1], a2 = hist[b4 + 2], a3 = hist[b4 + 3];
  int s = a0 + a1 + a2 + a3;
  ts[t] = s;
  __syncthreads();
  for (int off = 1; off < 256; off <<= 1) {
    int x = 0;
    if (t >= off) x = ts[t - off];
    __syncthreads();
    if (t >= off) ts[t] += x;
    __syncthreads();
  }
  int run = ts[t] - s;
  cur[b4] = run;
  cur[b4 + 1] = run + a0;
  cur[b4 + 2] = run + a0 + a1;
  cur[b4 + 3] = run + a0 + a1 + a2;
  __syncthreads();
  // deg_in for 128 nodes
  if (t < 128) {
    int n = node0 + t;
    if (n < N_NODES) {
      int sub = t >> 6, o = t & 7, row = (t >> 3) & 7;
      int base = (sub << 9) | (o << 3) | row;
      int dg = 0;
#pragma unroll
      for (int c = 0; c < 8; c++) dg += hist[base + (c << 6)];
      deg_in[n] = dg;
    }
  }
  // seg offsets: 2 agg blocks x 8 chunks x 8 owners = 128 entries
  if (t < 128) {
    int sub = t >> 6, c = (t >> 3) & 7, o = t & 7;
    seg[(bk * 2 + sub) * 64 + c * 8 + o] = e0 + cur[(sub << 9) | (c << 6) | (o << 3)];
  }
  __syncthreads();
  // scatter into eblk, repacked as (d6<<17)|src
  for (int j = e0 + t; j < e1; j += 256) {
    int v = sortedE[j];
    int d7 = v >> 17, sr = v & 0x1FFFF;
    int key = ((d7 >> 6) << 9) | ((sr >> 14) << 6) | ((d7 & 7) << 3) | ((d7 >> 3) & 7);
    int pos = e0 + atomicAdd(&cur[key], 1);
    eblk[pos] = ((d7 & 63) << 17) | sr;
  }
}

// ---------------- deg_out + per-graph counts (merged; saves a launch) ----------------
__global__ __launch_bounds__(256) void degout_c_k(const int* __restrict__ sortedS,
                                                  const int* __restrict__ bbase_src,
                                                  const int* __restrict__ node_graph,
                                                  int* __restrict__ deg_out,
                                                  float* __restrict__ counts) {
  __shared__ int h[128];
  __shared__ int hg[N_GRAPHS];
  int bk = blockIdx.x, t = threadIdx.x;
  if (t < 128) h[t] = 0;
  if (t < N_GRAPHS) hg[t] = 0;
  __syncthreads();
  int s0 = bbase_src[bk], s1 = bbase_src[bk + 1];
  for (int j = s0 + t; j < s1; j += 256) atomicAdd(&h[sortedS[j] & 127], 1);
  // per-graph counts for this block's node range
  if (t < 128) {
    int n = (bk << BSH) | t;
    if (n < N_NODES) atomicAdd(&hg[node_graph[n]], 1);
  }
  __syncthreads();
  if (t < 128) {
    int n = (bk << BSH) | t;
    if (n < N_NODES) deg_out[n] = h[t];
  }
  if (t < N_GRAPHS && hg[t]) atomicAdd(&counts[t], (float)hg[t]);
}

// ---------------- gemm1: out[n][c] = (X@W1)[n][c] * rsqrt(max(deg,1)), fp16 out ----
// No xs staging: within a wave all 16 column-lanes read the SAME X address ->
// hardware-broadcast global load (L1/L2 hit; each X element read exactly once per
// block). LDS = ws only (32.8KB) -> 4 blocks/CU (was 2 with xs) -> 16 waves/CU.
__global__ __launch_bounds__(256) void gemm1_k(const float* __restrict__ X,
                                               const float* __restrict__ W,
                                               const int* __restrict__ deg,
                                               __half* __restrict__ out) {
  __shared__ float ws[IN_DIM][HIDDEN];
  int t = threadIdx.x;
  int row0_blk = blockIdx.x * 64;

  for (int i = t; i < IN_DIM * HIDDEN / 4; i += 256)
    ((float4*)ws)[i] = ((const float4*)W)[i];
  __syncthreads();

  int w = t >> 6, lane = t & 63;
  int rg = lane >> 4, cg = lane & 15;
  int r0 = w * 16 + rg * 4;
  int c0 = cg * 4;
  int row_base = row0_blk + r0;
  bool full = (row_base + 3 < N_NODES);

  float acc[4][4];
#pragma unroll
  for (int i = 0; i < 4; i++)
#pragma unroll
    for (int j = 0; j < 4; j++) acc[i][j] = 0.f;

  const float zero4[4] = {0.f, 0.f, 0.f, 0.f};
#pragma unroll 4
  for (int d4 = 0; d4 < IN_DIM / 4; d4++) {
    float4 a0, a1, a2, a3;
    if (full) {
      a0 = *(const float4*)&X[(size_t)(row_base + 0) * IN_DIM + d4 * 4];
      a1 = *(const float4*)&X[(size_t)(row_base + 1) * IN_DIM + d4 * 4];
      a2 = *(const float4*)&X[(size_t)(row_base + 2) * IN_DIM + d4 * 4];
      a3 = *(const float4*)&X[(size_t)(row_base + 3) * IN_DIM + d4 * 4];
    } else {
      a0 = (row_base + 0 < N_NODES) ? *(const float4*)&X[(size_t)(row_base + 0) * IN_DIM + d4 * 4] : *(const float4*)zero4;
      a1 = (row_base + 1 < N_NODES) ? *(const float4*)&X[(size_t)(row_base + 1) * IN_DIM + d4 * 4] : *(const float4*)zero4;
      a2 = (row_base + 2 < N_NODES) ? *(const float4*)&X[(size_t)(row_base + 2) * IN_DIM + d4 * 4] : *(const float4*)zero4;
      a3 = (row_base + 3 < N_NODES) ? *(const float4*)&X[(size_t)(row_base + 3) * IN_DIM + d4 * 4] : *(const float4*)zero4;
    }
#pragma unroll
    for (int dd = 0; dd < 4; dd++) {
      float4 b = *(const float4*)&ws[d4 * 4 + dd][c0];
      float av0 = (&a0.x)[dd], av1 = (&a1.x)[dd], av2 = (&a2.x)[dd], av3 = (&a3.x)[dd];
      acc[0][0] += av0 * b.x; acc[0][1] += av0 * b.y; acc[0][2] += av0 * b.z; acc[0][3] += av0 * b.w;
      acc[1][0] += av1 * b.x; acc[1][1] += av1 * b.y; acc[1][2] += av1 * b.z; acc[1][3] += av1 * b.w;
      acc[2][0] += av2 * b.x; acc[2][1] += av2 * b.y; acc[2][2] += av2 * b.z; acc[2][3] += av2 * b.w;
      acc[3][0] += av3 * b.x; acc[3][1] += av3 * b.y; acc[3][2] += av3 * b.z; acc[3][3] += av3 * b.w;
    }
  }

#pragma unroll
  for (int i = 0; i < 4; i++) {
    int row = row_base + i;
    if (row >= N_NODES) continue;
    float dg = (float)deg[row];
    if (dg < 1.f) dg = 1.f;
    float sc = rsqrtf(dg);
    __half2 p0 = __floats2half2_rn(acc[i][0] * sc, acc[i][1] * sc);
    __half2 p1 = __floats2half2_rn(acc[i][2] * sc, acc[i][3] * sc);
    union { __half2 h2[2]; float2 f2; } u;
    u.h2[0] = p0; u.h2[1] = p1;
    *(float2*)&out[(size_t)row * HIDDEN + c0] = u.f2;
  }
}

// ---------------- aggregate: block=64 dst nodes, chunk-swept, owner-exclusive LDS ----
// ev (eblk word) prefetched one batch ahead. MODE 1: fuse gemm2 (W2 from global,
// L1-hot). MODE 2: fuse mean-pool partials. LDS ~17.7KB -> 8 blocks/CU -> all 1563
// blocks co-resident (required for the lockstep chunk sweep; see R11 post-mortem).
template <int MODE>
__global__ __launch_bounds__(256) void agg_seg_k(const __half* __restrict__ A,
                                                 const int* __restrict__ eblk,
                                                 const int* __restrict__ seg,
                                                 const int* __restrict__ deg_in,
                                                 const float* __restrict__ bias,
                                                 const float* __restrict__ W2,
                                                 const int* __restrict__ deg_out,
                                                 const int* __restrict__ node_graph,
                                                 float* __restrict__ sums,
                                                 __half* __restrict__ out) {
  __shared__ float acc[64][68];   // 17408 B
  __shared__ int ngs[64];
  __shared__ float psum[4][64];
  int bk = blockIdx.x, t = threadIdx.x;
  int o = t >> 5, l = t & 31;
  for (int i = t; i < 64 * 68; i += 256) ((float*)acc)[i] = 0.f;
  __syncthreads();
  int segbase = bk * 64;
  float rx = 0.f, ry = 0.f;
  int cur_d = -1;
#pragma unroll
  for (int c = 0; c < 8; c++) {
    int j0 = seg[segbase + c * 8 + o];
    int j1 = seg[segbase + c * 8 + o + 1];
    int j = j0;
    int ev = (j + 16 <= j1) ? eblk[j + (l & 15)] : 0;
    for (; j + 16 <= j1; ) {
      int ev_cur = ev;
      int jn = j + 16;
      if (jn + 16 <= j1) ev = eblk[jn + (l & 15)];  // prefetch next batch
      int vv[16];
#pragma unroll
      for (int k = 0; k < 16; k++) vv[k] = __shfl(ev_cur, k, 32);
      float2 ff[16];
#pragma unroll
      for (int k = 0; k < 16; k++)
        ff[k] = __half22float2(*(const __half2*)&A[(size_t)(vv[k] & 0x1FFFF) * HIDDEN + 2 * l]);
#pragma unroll
      for (int k = 0; k < 16; k++) {
        int d = vv[k] >> 17;
        if (d != cur_d) {
          if (cur_d >= 0) {
            float2* ap = (float2*)&acc[cur_d][2 * l];
            float2 a0 = *ap; a0.x += rx; a0.y += ry; *ap = a0;
          }
          cur_d = d; rx = 0.f; ry = 0.f;
        }
        rx += ff[k].x; ry += ff[k].y;
      }
      j = jn;
    }
    for (; j + 4 <= j1; j += 4) {
      int vv[4];
#pragma unroll
      for (int k = 0; k < 4; k++) vv[k] = eblk[j + k];
      float2 ff[4];
#pragma unroll
      for (int k = 0; k < 4; k++)
        ff[k] = __half22float2(*(const __half2*)&A[(size_t)(vv[k] & 0x1FFFF) * HIDDEN + 2 * l]);
#pragma unroll
      for (int k = 0; k < 4; k++) {
        int d = vv[k] >> 17;
        if (d != cur_d) {
          if (cur_d >= 0) {
            float2* ap = (float2*)&acc[cur_d][2 * l];
            float2 a0 = *ap; a0.x += rx; a0.y += ry; *ap = a0;
          }
          cur_d = d; rx = 0.f; ry = 0.f;
        }
        rx += ff[k].x; ry += ff[k].y;
      }
    }
    for (; j < j1; j++) {
      int v = eblk[j];
      int d = v >> 17;
      if (d != cur_d) {
        if (cur_d >= 0) {
          float2* ap = (float2*)&acc[cur_d][2 * l];
          float2 a0 = *ap; a0.x += rx; a0.y += ry; *ap = a0;
        }
        cur_d = d; rx = 0.f; ry = 0.f;
      }
      float2 f = __half22float2(*(const __half2*)&A[(size_t)(v & 0x1FFFF) * HIDDEN + 2 * l]);
      rx += f.x; ry += f.y;
    }
  }
  if (cur_d >= 0) {
    float2* ap = (float2*)&acc[cur_d][2 * l];
    float2 a0 = *ap; a0.x += rx; a0.y += ry; *ap = a0;
  }
  __syncthreads();

  int node0 = bk << 6;
  if constexpr (MODE == 1) {
    for (int i = t; i < 64 * 64; i += 256) {
      int r = i >> 6, ch = i & 63;
      float dg = (float)deg_in[node0 + r];
      if (dg < 1.f) dg = 1.f;
      float v = acc[r][ch] * rsqrtf(dg) + bias[ch];
      acc[r][ch] = v > 0.f ? v : 0.f;
    }
    __syncthreads();
    int w = t >> 6, lane = t & 63;
    int rg = lane >> 4, cg = lane & 15;
    int r0 = w * 16 + rg * 4;
    int c0 = cg * 4;
    float oacc[4][4];
#pragma unroll
    for (int i = 0; i < 4; i++)
#pragma unroll
      for (int j = 0; j < 4; j++) oacc[i][j] = 0.f;
#pragma unroll 4
    for (int d = 0; d < 64; d++) {
      float4 b = *(const float4*)&W2[d * HIDDEN + c0];
      float a0 = acc[r0 + 0][d], a1 = acc[r0 + 1][d];
      float a2 = acc[r0 + 2][d], a3 = acc[r0 + 3][d];
      oacc[0][0] += a0 * b.x; oacc[0][1] += a0 * b.y; oacc[0][2] += a0 * b.z; oacc[0][3] += a0 * b.w;
      oacc[1][0] += a1 * b.x; oacc[1][1] += a1 * b.y; oacc[1][2] += a1 * b.z; oacc[1][3] += a1 * b.w;
      oacc[2][0] += a2 * b.x; oacc[2][1] += a2 * b.y; oacc[2][2] += a2 * b.z; oacc[2][3] += a2 * b.w;
      oacc[3][0] += a3 * b.x; oacc[3][1] += a3 * b.y; oacc[3][2] += a3 * b.z; oacc[3][3] += a3 * b.w;
    }
#pragma unroll
    for (int i = 0; i < 4; i++) {
      int node = node0 + r0 + i;
      if (node >= N_NODES) continue;
      float dg = (float)deg_out[node];
      if (dg < 1.f) dg = 1.f;
      float sc = rsqrtf(dg);
      __half2 p0 = __floats2half2_rn(oacc[i][0] * sc, oacc[i][1] * sc);
      __half2 p1 = __floats2half2_rn(oacc[i][2] * sc, oacc[i][3] * sc);
      union { __half2 h2[2]; float2 f2; } u;
      u.h2[0] = p0; u.h2[1] = p1;
      *(float2*)&out[(size_t)node * HIDDEN + c0] = u.f2;
    }
  } else {
    if (t < 64) {
      int node = node0 + t;
      ngs[t] = (node < N_NODES) ? node_graph[node] : -1;
    }
    __syncthreads();
    int ch = t & 63, q = t >> 6;
    bool uniform = (ngs[0] >= 0) && (ngs[0] == ngs[63]);
    if (uniform) {
      float a = 0.f;
      for (int r = q * 16; r < q * 16 + 16; r++) {
        float dg = (float)deg_in[node0 + r];
        if (dg < 1.f) dg = 1.f;
        float v = acc[r][ch] * rsqrtf(dg) + bias[ch];
        a += (v > 0.f ? v : 0.f);
      }
      psum[q][ch] = a;
      __syncthreads();
      if (t < 64) {
        float s4 = psum[0][t] + psum[1][t] + psum[2][t] + psum[3][t];
        atomicAdd(&sums[ngs[0] * HIDDEN + t], s4);
      }
    } else {
      int curg = -1; float a = 0.f;
      for (int r = q * 16; r < q * 16 + 16; r++) {
        int g = ngs[r];
        if (g != curg) {
          if (curg >= 0) atomicAdd(&sums[curg * HIDDEN + ch], a);
          curg = g; a = 0.f;
        }
        if (g >= 0) {
          float dg = (float)deg_in[node0 + r];
          if (dg < 1.f) dg = 1.f;
          float v = acc[r][ch] * rsqrtf(dg) + bias[ch];
          a += (v > 0.f ? v : 0.f);
        }
      }
      if (curg >= 0) atomicAdd(&sums[curg * HIDDEN + ch], a);
    }
  }
}

// ---------------- final: h_graph = sums/counts; mu/logvar = h_graph @ Wmu/Wlv + b ----------------
__global__ __launch_bounds__(256) void final_k(const float* __restrict__ sums,
                                               const float* __restrict__ counts,
                                               const float* __restrict__ Wmu,
                                               const float* __restrict__ bmu,
                                               const float* __restrict__ Wlv,
                                               const float* __restrict__ blv,
                                               float* __restrict__ out) {
  __shared__ float hg[N_GRAPHS][HIDDEN];
  __shared__ float wmu[HIDDEN][LATENT];
  __shared__ float wlv[HIDDEN][LATENT];
  int t = threadIdx.x;
  for (int i = t; i < N_GRAPHS * HIDDEN; i += 256) {
    int g = i / HIDDEN;
    float c = counts[g];
    if (c < 1.f) c = 1.f;
    hg[g][i % HIDDEN] = sums[i] / c;
  }
  for (int i = t; i < HIDDEN * LATENT; i += 256) {
    wmu[i / LATENT][i % LATENT] = Wmu[i];
    wlv[i / LATENT][i % LATENT] = Wlv[i];
  }
  __syncthreads();
  for (int i = t; i < N_GRAPHS * LATENT; i += 256) {
    int g = i / LATENT, j = i % LATENT;
    float mu = bmu[j], lv = blv[j];
#pragma unroll
    for (int k = 0; k < HIDDEN; k++) {
      float v = hg[g][k];
      mu += v * wmu[k][j];
      lv += v * wlv[k][j];
    }
    out[i] = mu;
    out[N_GRAPHS * LATENT + i] = lv;
  }
}

extern "C" void kernel_launch(void* const* d_in, const int* in_sizes, int n_in,
                              void* d_out, int out_size, void* d_ws, size_t ws_size,
                              hipStream_t stream) {
  const float* x = (const float*)d_in[0];
  // d_in[1] = edge_feat: provably unused for (mu, logvar)
  const int* src = (const int*)d_in[2];
  const int* dst = (const int*)d_in[3];
  const int* node_graph = (const int*)d_in[4];
  const float* W1 = (const float*)d_in[5];
  const float* b1 = (const float*)d_in[6];
  const float* W2 = (const float*)d_in[7];
  const float* b2 = (const float*)d_in[8];
  // d_in[9] = We, d_in[10] = be: unused
  const float* Wmu = (const float*)d_in[11];
  const float* bmu = (const float*)d_in[12];
  const float* Wlv = (const float*)d_in[13];
  const float* blv = (const float*)d_in[14];
  float* out = (float*)d_out;

  char* ws = (char*)d_ws;
  // zeroed control block [0, 33280)
  int* bc_src   = (int*)(ws + 0);        // 4096
  int* bc_dst   = (int*)(ws + 4096);     // 4096
  int* cur_src  = (int*)(ws + 8192);     // 4096
  int* cur_dst  = (int*)(ws + 12288);    // 4096
  float* cnts   = (float*)(ws + 16384);  // 512
  float* sums   = (float*)(ws + 16896);  // 16384 -> 33280
  // non-zeroed control
  int* bbase_src = (int*)(ws + 33280);   // 4100 (pad 4352)
  int* bbase_dst = (int*)(ws + 37632);   // 4100 (pad)
  int* tbl_src   = (int*)(ws + 41984);   // 1048576
  int* tbl_dst   = (int*)(ws + 1090560); // 1048576 -> 2139136
  // big arrays
  int* deg_out = (int*)(ws + 2139136);   // 400128 -> 2539264
  int* deg_in  = (int*)(ws + 2539264);   // 400128 -> 2939392
  int* seg     = (int*)(ws + 2939392);   // SEG_INTS*4 = 400640 pad -> 3340800
  int* eblk    = (int*)(ws + 3340800);   // 12800000 -> 16140800
  int* sortedS = (int*)(ws + 16140800);  // 12800000 -> 28940800 (dead after degout)
  int* sortedE = (int*)(ws + 28940800);  // 12800000 -> 41740800 (dead after fine_sort)
  __half* A1   = (__half*)(ws + 16140800); // alias of sortedS (layer1 gemm out)
  __half* A2   = (__half*)(ws + 28940800); // alias of sortedE (fused agg1+gemm2 out)

  zero_k<<<(33280 / 16 + 255) / 256, 256, 0, stream>>>((int4*)ws, 33280 / 16);

  hist_c_k<<<SC_BLOCKS, 256, 0, stream>>>((const int4*)src, (const int4*)dst,
                                          bc_src, bc_dst, tbl_src, tbl_dst);
  scan_c_k<<<1, 256, 0, stream>>>(bc_src, bc_dst, bbase_src, bbase_dst);
  scatter_c_k<<<SC_BLOCKS, 256, 0, stream>>>((const int4*)src, (const int4*)dst,
                                             bbase_src, bbase_dst, tbl_src, tbl_dst,
                                             cur_src, cur_dst, sortedS, sortedE);
  fine_sort_k<<<NB_USED, 256, 0, stream>>>(sortedE, bbase_dst, deg_in, seg, eblk);
  degout_c_k<<<NB_USED, 256, 0, stream>>>(sortedS, bbase_src, node_graph, deg_out, cnts);

  const int GEMM_BLKS = (N_NODES + 63) / 64;  // 1563

  // layer 1 GEMM: A1 = fp16((x @ W1) * deg_out^-1/2)
  gemm1_k<<<GEMM_BLKS, 256, 0, stream>>>(x, W1, deg_out, A1);
  // fused agg1 + gemm2: A2 = fp16( (relu(agg(A1)*deg_in^-1/2 + b1) @ W2) * deg_out^-1/2 )
  agg_seg_k<1><<<NBLK_AGG, 256, 0, stream>>>(A1, eblk, seg, deg_in, b1, W2, deg_out,
                                             nullptr, nullptr, A2);
  // fused agg2 + mean-pool: sums += per-graph sums of relu(agg(A2)*deg_in^-1/2 + b2)
  agg_seg_k<2><<<NBLK_AGG, 256, 0, stream>>>(A2, eblk, seg, deg_in, b2, nullptr, nullptr,
                                             node_graph, sums, nullptr);

  final_k<<<1, 256, 0, stream>>>(sums, cnts, Wmu, bmu, Wlv, blv, out);
}